// Round 2
// baseline (35098.996 us; speedup 1.0000x reference)
//
#include <hip/hip_runtime.h>
#include <cmath>

#define BATCHN 64
#define SEQL   512
#define HD     512
#define NTAG   6
#define PAD_TAG 5
#define CHUNK  64

__device__ __forceinline__ float sigm(float x) { return 1.f / (1.f + expf(-x)); }

// ---------------- combined bias: bih + bhh ----------------
__global__ void k_bias(const float* __restrict__ a0, const float* __restrict__ c0,
                       const float* __restrict__ a1, const float* __restrict__ c1,
                       const float* __restrict__ a2, const float* __restrict__ c2,
                       const float* __restrict__ a3, const float* __restrict__ c3,
                       float* __restrict__ out) {
  int i = blockIdx.x * blockDim.x + threadIdx.x;   // 8192
  int w = i >> 11, r = i & 2047;
  float v;
  if (w == 0)      v = a0[r] + c0[r];
  else if (w == 1) v = a1[r] + c1[r];
  else if (w == 2) v = a2[r] + c2[r];
  else             v = a3[r] + c3[r];
  out[i] = v;
}

// ---------------- logits init: fc_b broadcast ----------------
__global__ void k_loginit(float* __restrict__ logits, const float* __restrict__ fcb) {
  int i = blockIdx.x * blockDim.x + threadIdx.x;   // 196608
  if (i < BATCHN * SEQL * NTAG) logits[i] = fcb[i % NTAG];
}

// ---------------- chunk GEMM: pre[r][2048] = A_row(r) . W^T + bias ----------------
// rows r = b*64 + tl (tl = step-tbase); A_row: layer0 = embed[text[b,src]], layer1 = h0cat[b,src]
// src = dir ? clamp(len-1-t,0) : t   (step-indexed pre: backward reversal folded in here)
template<int MODE>
__global__ __launch_bounds__(256) void k_gemm_pre(
    const float* __restrict__ embed, const float* __restrict__ h0,
    const int* __restrict__ text, const int* __restrict__ lengths,
    const float* __restrict__ W, const float* __restrict__ bias,
    float* __restrict__ pre, int tbase, int dir) {
  constexpr int K = MODE ? 1024 : 256;
  __shared__ __align__(16) float As[16][132];
  __shared__ __align__(16) float Bs[16][132];
  int bx = blockIdx.x & 15;   // 16 n-tiles of 128 (N=2048)
  int by = blockIdx.x >> 4;   // 32 m-tiles of 128 (M=4096)
  int m0 = by * 128, n0 = bx * 128;
  int tid = threadIdx.x;
  int lm = tid >> 2, lk = (tid & 3) * 4;
  int rm = (tid >> 4) * 8, rn = (tid & 15) * 8;

  const float* arow0;
  const float* arow1;
  {
    int r = m0 + lm; int b = r >> 6; int t = tbase + (r & 63);
    int src = dir ? max(lengths[b] - 1 - t, 0) : t;
    arow0 = MODE ? h0 + ((size_t)b * SEQL + src) * 1024
                 : embed + (size_t)text[b * SEQL + src] * 256;
    r = m0 + lm + 64; b = r >> 6; t = tbase + (r & 63);
    src = dir ? max(lengths[b] - 1 - t, 0) : t;
    arow1 = MODE ? h0 + ((size_t)b * SEQL + src) * 1024
                 : embed + (size_t)text[b * SEQL + src] * 256;
  }

  float acc[8][8] = {};
  for (int k0 = 0; k0 < K; k0 += 16) {
    float4 av0 = *(const float4*)(arow0 + k0 + lk);
    float4 av1 = *(const float4*)(arow1 + k0 + lk);
    float4 bv0 = *(const float4*)&W[(size_t)(n0 + lm) * K + k0 + lk];
    float4 bv1 = *(const float4*)&W[(size_t)(n0 + lm + 64) * K + k0 + lk];
    __syncthreads();
    As[lk + 0][lm] = av0.x; As[lk + 1][lm] = av0.y; As[lk + 2][lm] = av0.z; As[lk + 3][lm] = av0.w;
    As[lk + 0][lm + 64] = av1.x; As[lk + 1][lm + 64] = av1.y; As[lk + 2][lm + 64] = av1.z; As[lk + 3][lm + 64] = av1.w;
    Bs[lk + 0][lm] = bv0.x; Bs[lk + 1][lm] = bv0.y; Bs[lk + 2][lm] = bv0.z; Bs[lk + 3][lm] = bv0.w;
    Bs[lk + 0][lm + 64] = bv1.x; Bs[lk + 1][lm + 64] = bv1.y; Bs[lk + 2][lm + 64] = bv1.z; Bs[lk + 3][lm + 64] = bv1.w;
    __syncthreads();
#pragma unroll
    for (int k = 0; k < 16; ++k) {
      float4 a0v = *(const float4*)&As[k][rm];
      float4 a1v = *(const float4*)&As[k][rm + 4];
      float4 b0v = *(const float4*)&Bs[k][rn];
      float4 b1v = *(const float4*)&Bs[k][rn + 4];
      float a[8] = {a0v.x, a0v.y, a0v.z, a0v.w, a1v.x, a1v.y, a1v.z, a1v.w};
      float b[8] = {b0v.x, b0v.y, b0v.z, b0v.w, b1v.x, b1v.y, b1v.z, b1v.w};
#pragma unroll
      for (int i = 0; i < 8; ++i)
#pragma unroll
        for (int j = 0; j < 8; ++j)
          acc[i][j] = fmaf(a[i], b[j], acc[i][j]);
    }
  }
#pragma unroll
  for (int i = 0; i < 8; ++i) {
    size_t rowb = (size_t)(m0 + rm + i) * 2048 + n0 + rn;
#pragma unroll
    for (int j = 0; j < 8; ++j)
      pre[rowb + j] = acc[i][j] + bias[n0 + rn + j];
  }
}

// ---------------- one LSTM timestep, both directions ----------------
// grid 256 = 2 dirs x 128 slices(4 units); block 256 = 4 waves; wave=unit, lane=batch.
// States transposed: hT/cT [unit][batch] for coalesced lane access.
template<int LAYER>
__global__ __launch_bounds__(256) void k_step(
    const float* __restrict__ preF, const float* __restrict__ preB,
    const float* __restrict__ whhF, const float* __restrict__ whhB,
    const float* __restrict__ biasB,
    const int* __restrict__ lengths,
    float* __restrict__ cTF, float* __restrict__ cTB,
    const float* __restrict__ hFp, float* __restrict__ hFn,
    const float* __restrict__ hBp, float* __restrict__ hBn,
    float* __restrict__ h0cat, float* __restrict__ stage,
    const float* __restrict__ fcw, int t) {
  __shared__ float red[4][64][NTAG];
  int d = blockIdx.x >> 7, slice = blockIdx.x & 127;
  int w = threadIdx.x >> 6, b = threadIdx.x & 63;
  int j = slice * 4 + w;

  const float* hp = d ? hBp : hFp;
  const float* Wm = d ? whhB : whhF;
  const float* w0 = Wm + (size_t)j * HD;
  const float* w1 = Wm + (size_t)(HD + j) * HD;
  const float* w2 = Wm + (size_t)(2 * HD + j) * HD;
  const float* w3 = Wm + (size_t)(3 * HD + j) * HD;

  float a0 = 0.f, a1 = 0.f, a2 = 0.f, a3 = 0.f;
#pragma unroll 4
  for (int k = 0; k < HD; k += 4) {
    float h0v = hp[(k + 0) * 64 + b];
    float h1v = hp[(k + 1) * 64 + b];
    float h2v = hp[(k + 2) * 64 + b];
    float h3v = hp[(k + 3) * 64 + b];
    float4 q0 = *(const float4*)(w0 + k);
    float4 q1 = *(const float4*)(w1 + k);
    float4 q2 = *(const float4*)(w2 + k);
    float4 q3 = *(const float4*)(w3 + k);
    a0 = fmaf(q0.x, h0v, a0); a0 = fmaf(q0.y, h1v, a0); a0 = fmaf(q0.z, h2v, a0); a0 = fmaf(q0.w, h3v, a0);
    a1 = fmaf(q1.x, h0v, a1); a1 = fmaf(q1.y, h1v, a1); a1 = fmaf(q1.z, h2v, a1); a1 = fmaf(q1.w, h3v, a1);
    a2 = fmaf(q2.x, h0v, a2); a2 = fmaf(q2.y, h1v, a2); a2 = fmaf(q2.z, h2v, a2); a2 = fmaf(q2.w, h3v, a2);
    a3 = fmaf(q3.x, h0v, a3); a3 = fmaf(q3.y, h1v, a3); a3 = fmaf(q3.z, h2v, a3); a3 = fmaf(q3.w, h3v, a3);
  }

  int lenb = lengths[b];
  int tl = t & (CHUNK - 1);
  float p0, p1, p2, p3;
  if (d == 1 && t >= lenb) {
    // reference: backward input past valid length is zero -> pre = bih+bhh
    p0 = biasB[j]; p1 = biasB[HD + j]; p2 = biasB[2 * HD + j]; p3 = biasB[3 * HD + j];
  } else {
    const float* pr = (d ? preB : preF) + ((size_t)b * CHUNK + tl) * 2048;
    p0 = pr[j]; p1 = pr[HD + j]; p2 = pr[2 * HD + j]; p3 = pr[3 * HD + j];
  }
  float gi = p0 + a0, gf = p1 + a1, gg = p2 + a2, go = p3 + a3;
  float si = sigm(gi), sf = sigm(gf), tgv = tanhf(gg), so = sigm(go);
  float* cT = d ? cTB : cTF;
  float c = cT[j * 64 + b];
  float cn = sf * c + si * tgv;
  cT[j * 64 + b] = cn;
  float hn = so * tanhf(cn);
  (d ? hBn : hFn)[j * 64 + b] = hn;

  if (LAYER == 0) {
    if (t < lenb) {
      int pos = d ? (lenb - 1 - t) : t;
      h0cat[((size_t)b * SEQL + pos) * 1024 + d * HD + j] = hn;
    }
  } else {
    // fused FC: per-unit logit contribution, block-reduced over the 4 units
#pragma unroll
    for (int tg = 0; tg < NTAG; ++tg) red[w][b][tg] = fcw[tg * 1024 + d * HD + j] * hn;
    __syncthreads();
    if (w == 0) {
#pragma unroll
      for (int tg = 0; tg < NTAG; ++tg) {
        float s = red[0][b][tg] + red[1][b][tg] + red[2][b][tg] + red[3][b][tg];
        stage[(size_t)(d * 128 + slice) * 24576 + b * 384 + tl * 6 + tg] = s;
      }
    }
  }
}

// ---------------- deterministic logit reduction (per chunk) ----------------
__global__ __launch_bounds__(256) void k_redF(const float* __restrict__ stage,
                                              float* __restrict__ logits, int tbase) {
  int idx = blockIdx.x * 256 + threadIdx.x;  // 64*64*6 = 24576
  if (idx >= 64 * 64 * 6) return;
  int b = idx / 384; int r = idx % 384; int tl = r / 6, tg = r % 6;
  float s = 0.f;
#pragma unroll 8
  for (int sl = 0; sl < 128; ++sl)
    s += stage[(size_t)sl * 24576 + b * 384 + tl * 6 + tg];
  logits[((size_t)b * SEQL + tbase + tl) * 6 + tg] += s;
}

__global__ __launch_bounds__(256) void k_redB(const float* __restrict__ stage,
                                              float* __restrict__ logits,
                                              const int* __restrict__ lengths, int tbase) {
  int idx = blockIdx.x * 256 + threadIdx.x;
  if (idx >= 64 * 64 * 6) return;
  int b = idx / 384; int r = idx % 384; int tl = r / 6, tg = r % 6;
  int t = tbase + tl;
  int lenb = lengths[b];
  if (t >= lenb) return;  // backward contributions past valid length are dropped (ref: zeros)
  float s = 0.f;
#pragma unroll 8
  for (int sl = 0; sl < 128; ++sl)
    s += stage[(size_t)(128 + sl) * 24576 + b * 384 + tl * 6 + tg];
  logits[((size_t)b * SEQL + (lenb - 1 - t)) * 6 + tg] += s;
}

// ---------------- softmax ----------------
__global__ __launch_bounds__(256) void k_softmax(const float* __restrict__ logits,
                                                 float* __restrict__ probs) {
  int p = blockIdx.x * 256 + threadIdx.x;   // 32768 positions
  if (p >= BATCHN * SEQL) return;
  const float* l = logits + (size_t)p * 6;
  float mx = l[0];
#pragma unroll
  for (int k = 1; k < NTAG; ++k) mx = fmaxf(mx, l[k]);
  float e[NTAG], s = 0.f;
#pragma unroll
  for (int k = 0; k < NTAG; ++k) { e[k] = expf(l[k] - mx); s += e[k]; }
#pragma unroll
  for (int k = 0; k < NTAG; ++k) probs[(size_t)p * 6 + k] = e[k] / s;
}

// ---------------- Viterbi (exact reference semantics) ----------------
__global__ void k_viterbi(const float* __restrict__ probs,
                          const int* __restrict__ lengths,
                          const float* __restrict__ crf_start,
                          const float* __restrict__ crf_end,
                          const float* __restrict__ crf_trans,
                          int* __restrict__ hist,
                          int* __restrict__ out) {
  int b = threadIdx.x;
  if (b >= BATCHN) return;
  const float* em = probs + (size_t)b * SEQL * NTAG;
  int* hb = hist + (size_t)b * SEQL * NTAG;
  int len = lengths[b];
  float sc[NTAG];
#pragma unroll
  for (int k = 0; k < NTAG; ++k) sc[k] = crf_start[k] + em[k];
  for (int t = 1; t < SEQL; ++t) {
    float ns[NTAG];
#pragma unroll
    for (int k = 0; k < NTAG; ++k) {
      float e = em[t * NTAG + k];
      float best = (sc[0] + crf_trans[0 * NTAG + k]) + e;
      int bi = 0;
#pragma unroll
      for (int jj = 1; jj < NTAG; ++jj) {
        float v = (sc[jj] + crf_trans[jj * NTAG + k]) + e;
        if (v > best) { best = v; bi = jj; }   // first-max tie rule (jnp.argmax)
      }
      ns[k] = best;
      hb[t * NTAG + k] = bi;
    }
    if (t < len) {
#pragma unroll
      for (int k = 0; k < NTAG; ++k) sc[k] = ns[k];
    }
  }
  float bv = sc[0] + crf_end[0];
  int bl = 0;
#pragma unroll
  for (int jj = 1; jj < NTAG; ++jj) {
    float v = sc[jj] + crf_end[jj];
    if (v > bv) { bv = v; bl = jj; }
  }
  int carry = 0;
  for (int t = SEQL - 1; t >= 0; --t) {
    int back = (t < SEQL - 1) ? hb[(t + 1) * NTAG + carry] : 0;
    int tag = (t == len - 1) ? bl : back;
    out[(size_t)b * SEQL + t] = (t <= len - 1) ? tag : PAD_TAG;
    carry = tag;
  }
}

// ---------------- fallback (ws too small: benign wrong answer, no fault) ----------------
__global__ void k_fallback(int* __restrict__ out) {
  int i = blockIdx.x * 256 + threadIdx.x;
  if (i < BATCHN * SEQL) out[i] = PAD_TAG;
}

// ---------------- launch ----------------
extern "C" void kernel_launch(void* const* d_in, const int* in_sizes, int n_in,
                              void* d_out, int out_size, void* d_ws, size_t ws_size,
                              hipStream_t stream) {
  (void)in_sizes; (void)n_in; (void)out_size;
  const int*   text    = (const int*)d_in[0];
  const int*   lengths = (const int*)d_in[1];
  const float* embed   = (const float*)d_in[3];
  const float* wih0f = (const float*)d_in[4];
  const float* whh0f = (const float*)d_in[5];
  const float* bih0f = (const float*)d_in[6];
  const float* bhh0f = (const float*)d_in[7];
  const float* wih0b = (const float*)d_in[8];
  const float* whh0b = (const float*)d_in[9];
  const float* bih0b = (const float*)d_in[10];
  const float* bhh0b = (const float*)d_in[11];
  const float* wih1f = (const float*)d_in[12];
  const float* whh1f = (const float*)d_in[13];
  const float* bih1f = (const float*)d_in[14];
  const float* bhh1f = (const float*)d_in[15];
  const float* wih1b = (const float*)d_in[16];
  const float* whh1b = (const float*)d_in[17];
  const float* bih1b = (const float*)d_in[18];
  const float* bhh1b = (const float*)d_in[19];
  const float* fc_w  = (const float*)d_in[20];
  const float* fc_b  = (const float*)d_in[21];
  const float* crf_s = (const float*)d_in[22];
  const float* crf_e = (const float*)d_in[23];
  const float* crf_t = (const float*)d_in[24];

  // workspace layout (floats); total 57,417,728 f = 229.7 MB
  const size_t need = 57417728ull * 4ull;
  if (ws_size < need) {
    k_fallback<<<128, 256, 0, stream>>>((int*)d_out);
    return;
  }
  float* ws = (float*)d_ws;
  float* h0cat  = ws;                        // 33,554,432
  float* preF   = h0cat + 33554432ull;       //  8,388,608
  float* preB   = preF  + 8388608ull;        //  8,388,608
  float* states = preB  + 8388608ull;        //    196,608
  float* cTF = states;
  float* cTB = cTF + 32768;
  float* hF0 = cTB + 32768;
  float* hF1 = hF0 + 32768;
  float* hB0 = hF1 + 32768;
  float* hB1 = hB0 + 32768;
  float* biasc  = states + 196608;           //      8,192
  float* stage  = biasc + 8192;              //  6,291,456
  float* logits = stage + 6291456ull;        //    196,608
  float* probs  = logits + 196608;           //    196,608
  int*   hist   = (int*)(probs + 196608);    //    196,608 ints

  k_bias<<<32, 256, 0, stream>>>(bih0f, bhh0f, bih0b, bhh0b, bih1f, bhh1f, bih1b, bhh1b, biasc);
  k_loginit<<<768, 256, 0, stream>>>(logits, fc_b);

  for (int L = 0; L < 2; ++L) {
    const float* whhF_ = L ? whh1f : whh0f;
    const float* whhB_ = L ? whh1b : whh0b;
    const float* wihF_ = L ? wih1f : wih0f;
    const float* wihB_ = L ? wih1b : wih0b;
    const float* biasF_ = biasc + (L ? 4096 : 0);
    const float* biasB_ = biasc + (L ? 6144 : 2048);

    hipMemsetAsync(states, 0, 196608ull * 4, stream);

    for (int c = 0; c < 8; ++c) {
      int tbase = c * CHUNK;
      if (L == 0) {
        k_gemm_pre<0><<<512, 256, 0, stream>>>(embed, nullptr, text, lengths, wihF_, biasF_, preF, tbase, 0);
        k_gemm_pre<0><<<512, 256, 0, stream>>>(embed, nullptr, text, lengths, wihB_, biasB_, preB, tbase, 1);
      } else {
        k_gemm_pre<1><<<512, 256, 0, stream>>>(nullptr, h0cat, text, lengths, wihF_, biasF_, preF, tbase, 0);
        k_gemm_pre<1><<<512, 256, 0, stream>>>(nullptr, h0cat, text, lengths, wihB_, biasB_, preB, tbase, 1);
      }
      for (int tl = 0; tl < CHUNK; ++tl) {
        int t = tbase + tl;
        const float* hFp = (t & 1) ? hF1 : hF0;  float* hFn = (t & 1) ? hF0 : hF1;
        const float* hBp = (t & 1) ? hB1 : hB0;  float* hBn = (t & 1) ? hB0 : hB1;
        if (L == 0)
          k_step<0><<<256, 256, 0, stream>>>(preF, preB, whhF_, whhB_, biasB_, lengths,
                                             cTF, cTB, hFp, hFn, hBp, hBn,
                                             h0cat, stage, fc_w, t);
        else
          k_step<1><<<256, 256, 0, stream>>>(preF, preB, whhF_, whhB_, biasB_, lengths,
                                             cTF, cTB, hFp, hFn, hBp, hBn,
                                             h0cat, stage, fc_w, t);
      }
      if (L == 1) {
        k_redF<<<96, 256, 0, stream>>>(stage, logits, tbase);
        k_redB<<<96, 256, 0, stream>>>(stage, logits, lengths, tbase);
      }
    }
  }

  k_softmax<<<128, 256, 0, stream>>>(logits, probs);
  k_viterbi<<<1, 64, 0, stream>>>(probs, lengths, crf_s, crf_e, crf_t, hist, (int*)d_out);
}